// Round 20
// baseline (188.404 us; speedup 1.0000x reference)
//
#include <hip/hip_runtime.h>
#include <hip/hip_bf16.h>
#include <cstdint>

typedef unsigned short u16;
typedef unsigned int   u32;
typedef __bf16  bf16x8 __attribute__((ext_vector_type(8)));
typedef __bf16  bf16x2 __attribute__((ext_vector_type(2)));
typedef float   f32x4  __attribute__((ext_vector_type(4)));
typedef unsigned short u16x4 __attribute__((ext_vector_type(4)));
typedef unsigned short u16x8 __attribute__((ext_vector_type(8)));
typedef unsigned int   u32x2 __attribute__((ext_vector_type(2)));

#define GLB(p) ((__attribute__((address_space(1))) void*)(p))
#define LDSP(p) ((__attribute__((address_space(3))) void*)(p))

__device__ __forceinline__ u16 f2bf(float f) {
  u32 u = __builtin_bit_cast(u32, f);
  u32 r = u + 0x7fffu + ((u >> 16) & 1u);
  return (u16)(r >> 16);
}

// raw 2^x via the COMPILER-VISIBLE builtin (hazard-safe; R13 lesson).
__device__ __forceinline__ float fexp2(float x) {
#if __has_builtin(__builtin_amdgcn_exp2f)
  return __builtin_amdgcn_exp2f(x);
#else
  float r;
  asm volatile("v_exp_f32 %0, %1\n\ts_nop 1" : "=v"(r) : "v"(x));
  return r;
#endif
}

__device__ __forceinline__ void cvt8(const float* __restrict__ in,
                                     u16* __restrict__ out, int i) {
  f32x4 a = *(const f32x4*)(in + i);
  f32x4 b = *(const f32x4*)(in + i + 4);
  u16x8 o;
#pragma unroll
  for (int j = 0; j < 4; ++j) { o[j] = f2bf(a[j]); o[4 + j] = f2bf(b[j]); }
  *(u16x8*)(out + i) = o;
}

// ---- fused prep: x/w_in/w_out f32->bf16 + mask->weights (1 launch) ----
__global__ __launch_bounds__(256) void prep(
    const float* __restrict__ x, u16* __restrict__ xbf,
    const float* __restrict__ wi, u16* __restrict__ wbf,
    const float* __restrict__ wo, u16* __restrict__ owbf,
    const float* __restrict__ mask, float* __restrict__ wf,
    u16* __restrict__ wpb) {
  const int blk = blockIdx.x, tid = threadIdx.x;
  if (blk < 4096) {
    cvt8(x, xbf, (blk * 256 + tid) * 8);
  } else if (blk < 5632) {
    cvt8(wi, wbf, ((blk - 4096) * 256 + tid) * 8);
  } else if (blk < 6144) {
    cvt8(wo, owbf, ((blk - 5632) * 256 + tid) * 8);
  } else {
    int i = (blk - 6144) * 256 + tid;
    float m = mask[i] * 1.4426950408889634f - 8.0f;
    float w = exp2f(m);
    wf[i] = w;
    int lp = (((i >> 2) & 3) << 3) | (((i >> 4) & 1) << 2) | (i & 3);
    wpb[(i & ~31) | lp] = f2bf(w);
  }
}

// ---------------- GEMM C = A * B^T (+bias), bf16 MFMA ----------------
// BK=32 double-buffered, T3 MINIMUM 2-PHASE sync (guide recipe):
//   STAGE(next) -> COMPUTE(cur) -> vmcnt(0)+s_barrier.
// The drain is issued AFTER compute so the next tile's loads hide under the
// 16 MFMAs; vmcnt(0) BEFORE the barrier gives cross-wave visibility (R19's
// counted-vmcnt-before-compute ordering raced: vmcnt is per-wave).
// LDS per buffer 16KB: rows folded 2-per-128B; proven conflict-free pattern.
// B rows permuted at staging (packed stores). XCD swizzle. K must be 1024.
__global__ __launch_bounds__(256) void gemm_bt(
    const u16* __restrict__ A, const u16* __restrict__ B,
    const float* __restrict__ bias,
    float* __restrict__ Cf, u16* __restrict__ Cq,
    int M, int N, int K, int mode) {
  __shared__ char lds[32768];   // buf0 @0 (A 8K, B 8K), buf1 @16384
  const int tid  = threadIdx.x;
  const int lane = tid & 63;
  const int wave = tid >> 6;

  const int lin = blockIdx.x;
  const int cpx = gridDim.x >> 3;
  const int w   = (lin & 7) * cpx + (lin >> 3);
  const int NB  = N >> 7;
  const int m0  = (w / NB) * 128;
  const int n0  = (w % NB) * 128;

  const int wr = (wave >> 1) * 64;
  const int wc = (wave & 1) * 64;

  // staging sources (pre-swizzled). chunk c2: row' = c2>>3, phys granule c2&7
  // holds logical lg = (c2&7)^(row'&7); lg = (rowblock<<2)|ksub.
  const u16* gA[2];
  const u16* gB[2];
  int oA[2], oB[2];
#pragma unroll
  for (int it = 0; it < 2; ++it) {
    int c2 = it * 256 + tid;
    int rp = c2 >> 3;
    int lg = (c2 & 7) ^ (rp & 7);
    int ra = rp + 64 * (lg >> 2);
    int ks = (lg & 3) * 8;
    gA[it] = A + (size_t)(m0 + ra) * K + ks;
    int p  = ra;
    int rb = 64 * (p >> 6) + 4 * (p & 15) + ((p >> 4) & 3);  // B col perm
    gB[it] = B + (size_t)(n0 + rb) * K + ks;
    oA[it] = c2 * 16;
    oB[it] = 8192 + c2 * 16;
  }

  // LDS read offsets (per-lane constants)
  const int L = lane & 15, g = lane >> 4;
  int aoff[4], boff[4];
#pragma unroll
  for (int i = 0; i < 4; ++i) {
    int R = wr + L + 16 * i;
    aoff[i] = (R & 63) * 128 + ((4 * (R >> 6) + g) ^ (R & 7)) * 16;
  }
#pragma unroll
  for (int j = 0; j < 4; ++j) {
    int P = wc + L + 16 * j;
    boff[j] = 8192 + (P & 63) * 128 + ((4 * (P >> 6) + g) ^ (P & 7)) * 16;
  }

  f32x4 acc[4][4] = {};

#define STAGE(SEL, T)                                                          \
  do {                                                                         \
    __builtin_amdgcn_global_load_lds(GLB(gA[0] + (T) * 32),                    \
                                     LDSP(lds + (SEL) * 16384 + oA[0]), 16, 0, 0); \
    __builtin_amdgcn_global_load_lds(GLB(gA[1] + (T) * 32),                    \
                                     LDSP(lds + (SEL) * 16384 + oA[1]), 16, 0, 0); \
    __builtin_amdgcn_global_load_lds(GLB(gB[0] + (T) * 32),                    \
                                     LDSP(lds + (SEL) * 16384 + oB[0]), 16, 0, 0); \
    __builtin_amdgcn_global_load_lds(GLB(gB[1] + (T) * 32),                    \
                                     LDSP(lds + (SEL) * 16384 + oB[1]), 16, 0, 0); \
  } while (0)

// drain-then-barrier: all waves' outstanding global_load_lds land, then sync.
#define SYNCB                                                                  \
  do {                                                                         \
    asm volatile("s_waitcnt vmcnt(0)" ::: "memory");                           \
    __builtin_amdgcn_sched_barrier(0);                                         \
    __builtin_amdgcn_s_barrier();                                              \
    __builtin_amdgcn_sched_barrier(0);                                         \
  } while (0)

#define COMPUTE(SEL)                                                           \
  do {                                                                         \
    bf16x8 af[4], bfr[4];                                                      \
    _Pragma("unroll") for (int i = 0; i < 4; ++i)                              \
      af[i] = *(const bf16x8*)(lds + (SEL) * 16384 + aoff[i]);                 \
    _Pragma("unroll") for (int j = 0; j < 4; ++j)                              \
      bfr[j] = *(const bf16x8*)(lds + (SEL) * 16384 + boff[j]);                \
    _Pragma("unroll") for (int i = 0; i < 4; ++i)                              \
      _Pragma("unroll") for (int j = 0; j < 4; ++j)                            \
        acc[i][j] = __builtin_amdgcn_mfma_f32_16x16x32_bf16(af[i], bfr[j],     \
                                                            acc[i][j], 0, 0, 0); \
  } while (0)

  // 32 K-tiles of 32 (K == 1024). Guide T3 2-phase: stage next BEFORE compute,
  // drain+barrier AFTER compute (latency hidden under the 16 MFMAs).
  STAGE(0, 0);
  SYNCB;
  for (int tt = 0; tt < 15; ++tt) {
    STAGE(1, 2 * tt + 1);
    COMPUTE(0);
    SYNCB;
    STAGE(0, 2 * tt + 2);
    COMPUTE(1);
    SYNCB;
  }
  STAGE(1, 31);
  COMPUTE(0);
  SYNCB;
  COMPUTE(1);

  const int r0 = m0 + wr + (lane >> 4) * 4;
  const int c0 = n0 + wc + L * 4;
  f32x4 bv4 = *(const f32x4*)(bias + c0);
  const float qs = (c0 < 1024) ? 0.18033688011112042f : 1.0f;
  const int sect = c0 >> 10, rem = c0 & 1023;
  const int hh = rem >> 6, dd = rem & 63;
#pragma unroll
  for (int i = 0; i < 4; ++i) {
#pragma unroll
    for (int r = 0; r < 4; ++r) {
      int row = r0 + i * 16 + r;
      f32x4 v;
#pragma unroll
      for (int j = 0; j < 4; ++j) v[j] = acc[i][j][r] + bv4[j];
      if (mode == 0) {
        *(f32x4*)(Cf + (size_t)row * N + c0) = v;
      } else {
        u16x4 o;
#pragma unroll
        for (int j = 0; j < 4; ++j) o[j] = f2bf(v[j] * qs);
        int bb = row >> 11, tt2 = row & 2047;
        *(u16x4*)(Cq + (((((size_t)sect * 4 + bb) * 16 + hh) * 2048 + tt2) * 64 + dd)) = o;
      }
    }
  }
#undef STAGE
#undef SYNCB
#undef COMPUTE
}

// ---- V transpose + weight-fold + sigma key-perm: [bh][t][d] -> [bh][d][t'] ----
__global__ __launch_bounds__(256) void transv(const u16* __restrict__ Vp,
                                              u16* __restrict__ Vt,
                                              const float* __restrict__ wf) {
  __shared__ u16 tl[64][68];
  const int tid = threadIdx.x;
  const int bh  = blockIdx.y;
  const int b   = bh >> 4;
  const int t0  = blockIdx.x * 64;
  const u16* src = Vp + ((size_t)bh * 2048 + t0) * 64;
  const float* wrow = wf + (size_t)b * 2048 + t0;
#pragma unroll
  for (int it = 0; it < 2; ++it) {
    int c = it * 256 + tid;
    int r = c >> 3, ch = c & 7;
    u16x8 v = *(const u16x8*)(src + r * 64 + ch * 8);
    float wv = wrow[r];
#pragma unroll
    for (int j = 0; j < 8; ++j) {
      float f = __builtin_bit_cast(float, ((u32)v[j]) << 16) * wv;
      tl[r][ch * 8 + j] = f2bf(f);
    }
  }
  __syncthreads();
  u16* dst = Vt + (size_t)bh * 64 * 2048 + t0;
#pragma unroll
  for (int it = 0; it < 2; ++it) {
    int c = it * 256 + tid;
    int d = c >> 3, ch = c & 7;
    int base = 32 * (ch >> 2) + 4 * (ch & 3);
    u16x8 v;
#pragma unroll
    for (int j = 0; j < 8; ++j) v[j] = tl[base + 16 * (j >> 2) + (j & 3)][d];
    *(u16x8*)(dst + (size_t)d * 2048 + ch * 8) = v;
  }
}

// ---- flash attention fwd (R18 measured-best, unchanged) ----
__global__ __launch_bounds__(512, 8) void attn_fwd(
    const u16* __restrict__ Qp, const u16* __restrict__ Kp,
    const u16* __restrict__ Vt, const u16* __restrict__ wpb,
    u16* __restrict__ AO) {
  __shared__ char lds[36864];
  const int tid  = threadIdx.x;
  const int lane = tid & 63;
  const int wave = tid >> 6;
  const int q15  = lane & 15;
  const int g    = lane >> 4;
  const int sw   = lane & 7;

  const int s  = blockIdx.x;
  const int w  = (s & 7) * 128 + (s >> 3);
  const int qt = w & 15;
  const int bh = w >> 4;
  const int b  = bh >> 4;
  const int h  = bh & 15;
  const int q0 = qt * 128;

  const u16* Qbase = Qp + ((size_t)bh * 2048 + q0) * 64;
  const u16* Kbase = Kp + (size_t)bh * 2048 * 64;
  const u16* Vbase = Vt + (size_t)bh * 64 * 2048;
  const u16* wrow  = wpb + (size_t)b * 2048;

  const u16* gK;
  const u16* gV;
  int ldso;
  {
    int c = tid;
    int r = c >> 3;
    int ch = (c & 7) ^ (r & 7);
    gK = Kbase + (size_t)r * 64 + ch * 8;
    gV = Vbase + (size_t)r * 2048 + ch * 8;
    ldso = c * 16;
  }

#define STAGE(SEL, KVV)                                                        \
  do {                                                                         \
    __builtin_amdgcn_global_load_lds(GLB(gK + (size_t)(KVV) * 64),             \
                                     LDSP(lds + (SEL) * 8192 + ldso), 16, 0, 0); \
    __builtin_amdgcn_global_load_lds(GLB(gV + (KVV)),                          \
                                     LDSP(lds + 16384 + (SEL) * 8192 + ldso), 16, 0, 0); \
  } while (0)

  bf16x8 qa0, qa1;
  {
    int qrow = wave * 16 + q15;
    qa0 = __builtin_bit_cast(bf16x8, *(const u16x8*)(Qbase + qrow * 64 + 8 * g));
    qa1 = __builtin_bit_cast(bf16x8, *(const u16x8*)(Qbase + qrow * 64 + 32 + 8 * g));
  }

  f32x4 oacc0 = {}, oacc1 = {}, oacc2 = {}, oacc3 = {};
  f32x4 lsum = {};
  const f32x4 z4 = {};

  const int koff0 = ((g) ^ sw) << 4;
  const int koff1 = ((4 + g) ^ sw) << 4;
  const char* pk0 = lds + q15 * 128 + koff0;
  const char* pk1 = lds + q15 * 128 + koff1;
  const char* pv0 = lds + 16384 + q15 * 128 + koff0;
  const char* pv1 = lds + 16384 + q15 * 128 + koff1;
  const char* pw  = lds + 32768 + 16 * g;

#define MFMA16(A, B, C) __builtin_amdgcn_mfma_f32_16x16x32_bf16((A), (B), (C), 0, 0, 0)

#define COMPUTE(SEL, KVV)                                                      \
  do {                                                                         \
    f32x4 sv0, sv1, sv2, sv3;                                                  \
    sv0 = MFMA16(*(const bf16x8*)(pk0 + (SEL) * 8192 + 0 * 2048), qa0, z4);    \
    sv0 = MFMA16(*(const bf16x8*)(pk1 + (SEL) * 8192 + 0 * 2048), qa1, sv0);   \
    sv1 = MFMA16(*(const bf16x8*)(pk0 + (SEL) * 8192 + 1 * 2048), qa0, z4);    \
    sv1 = MFMA16(*(const bf16x8*)(pk1 + (SEL) * 8192 + 1 * 2048), qa1, sv1);   \
    sv2 = MFMA16(*(const bf16x8*)(pk0 + (SEL) * 8192 + 2 * 2048), qa0, z4);    \
    sv2 = MFMA16(*(const bf16x8*)(pk1 + (SEL) * 8192 + 2 * 2048), qa1, sv2);   \
    sv3 = MFMA16(*(const bf16x8*)(pk0 + (SEL) * 8192 + 3 * 2048), qa0, z4);    \
    sv3 = MFMA16(*(const bf16x8*)(pk1 + (SEL) * 8192 + 3 * 2048), qa1, sv3);   \
    _Pragma("unroll") for (int i = 0; i < 4; ++i) {                            \
      sv0[i] = fexp2(sv0[i]);                                                  \
      sv1[i] = fexp2(sv1[i]);                                                  \
      sv2[i] = fexp2(sv2[i]);                                                  \
      sv3[i] = fexp2(sv3[i]);                                                  \
    }                                                                          \
    bf16x8 pa0, pa1;                                                           \
    {                                                                          \
      u16x8 t0, t1;                                                            \
      _Pragma("unroll") for (int e = 0; e < 4; ++e) {                          \
        t0[e]     = __builtin_bit_cast(u16, (__bf16)sv0[e]);                   \
        t0[4 + e] = __builtin_bit_cast(u16, (__bf16)sv1[e]);                   \
        t1[e]     = __builtin_bit_cast(u16, (__bf16)sv2[e]);                   \
        t1[4 + e] = __builtin_bit_cast(u16, (__bf16)sv3[e]);                   \
      }                                                                        \
      pa0 = __builtin_bit_cast(bf16x8, t0);                                    \
      pa1 = __builtin_bit_cast(bf16x8, t1);                                    \
    }                                                                          \
    lsum = MFMA16(*(const bf16x8*)(pw + (KVV) * 2), pa0, lsum);                \
    lsum = MFMA16(*(const bf16x8*)(pw + (KVV) * 2 + 64), pa1, lsum);           \
    oacc0 = MFMA16(*(const bf16x8*)(pv0 + (SEL) * 8192 + 0 * 2048), pa0, oacc0); \
    oacc0 = MFMA16(*(const bf16x8*)(pv1 + (SEL) * 8192 + 0 * 2048), pa1, oacc0); \
    oacc1 = MFMA16(*(const bf16x8*)(pv0 + (SEL) * 8192 + 1 * 2048), pa0, oacc1); \
    oacc1 = MFMA16(*(const bf16x8*)(pv1 + (SEL) * 8192 + 1 * 2048), pa1, oacc1); \
    oacc2 = MFMA16(*(const bf16x8*)(pv0 + (SEL) * 8192 + 2 * 2048), pa0, oacc2); \
    oacc2 = MFMA16(*(const bf16x8*)(pv1 + (SEL) * 8192 + 2 * 2048), pa1, oacc2); \
    oacc3 = MFMA16(*(const bf16x8*)(pv0 + (SEL) * 8192 + 3 * 2048), pa0, oacc3); \
    oacc3 = MFMA16(*(const bf16x8*)(pv1 + (SEL) * 8192 + 3 * 2048), pa1, oacc3); \
  } while (0)

  STAGE(0, 0);
  if (tid < 256)
    __builtin_amdgcn_global_load_lds(GLB(wrow + tid * 8), LDSP(lds + 32768 + tid * 16), 16, 0, 0);
  __syncthreads();

  for (int kv = 0; kv < 2048; kv += 128) {
    if (kv + 64 < 2048) STAGE(1, kv + 64);
    COMPUTE(0, kv);
    __syncthreads();
    if (kv + 128 < 2048) STAGE(0, kv + 128);
    COMPUTE(1, kv + 64);
    __syncthreads();
  }

  float linv = 1.0f / lsum[0];
  int t = q0 + wave * 16 + q15;
  u16* aorow = AO + ((size_t)b * 2048 + t) * 1024 + h * 64 + 4 * g;
#pragma unroll
  for (int n = 0; n < 4; ++n) {
    const f32x4& oc = (n == 0) ? oacc0 : (n == 1) ? oacc1 : (n == 2) ? oacc2 : oacc3;
    bf16x2 lo = {(__bf16)(oc[0] * linv), (__bf16)(oc[1] * linv)};
    bf16x2 hi = {(__bf16)(oc[2] * linv), (__bf16)(oc[3] * linv)};
    *(u32*)(aorow + 16 * n)     = __builtin_bit_cast(u32, lo);
    *(u32*)(aorow + 16 * n + 2) = __builtin_bit_cast(u32, hi);
  }
#undef STAGE
#undef COMPUTE
#undef MFMA16
}

// ---------------- launch ----------------
extern "C" void kernel_launch(void* const* d_in, const int* in_sizes, int n_in,
                              void* d_out, int out_size, void* d_ws, size_t ws_size,
                              hipStream_t stream) {
  const float* x     = (const float*)d_in[0];
  const float* mask  = (const float*)d_in[1];
  const float* w_in  = (const float*)d_in[2];
  const float* b_in  = (const float*)d_in[3];
  const float* w_out = (const float*)d_in[4];
  const float* b_out = (const float*)d_in[5];
  float* out = (float*)d_out;

  u16* xbf  = (u16*)d_ws;
  u16* wbf  = xbf  + (size_t)8192 * 1024;
  u16* owbf = wbf  + (size_t)3072 * 1024;
  u16* qkvp = owbf + (size_t)1024 * 1024;
  u16* vt   = qkvp + (size_t)3 * 8192 * 1024;
  u16* ao   = vt   + (size_t)8192 * 1024;
  float* wf = (float*)(ao + (size_t)8192 * 1024);
  u16* wpb  = (u16*)(wf + 8192);

  prep<<<6176, 256, 0, stream>>>(x, xbf, w_in, wbf, w_out, owbf, mask, wf, wpb);

  gemm_bt<<<1536, 256, 0, stream>>>(xbf, wbf, b_in, nullptr, qkvp,
                                    8192, 3072, 1024, 1);
  transv<<<dim3(32, 64), 256, 0, stream>>>(qkvp + (size_t)2 * 8192 * 1024, vt, wf);
  attn_fwd<<<1024, 512, 0, stream>>>(qkvp, qkvp + (size_t)8192 * 1024,
                                     vt, wpb, ao);
  gemm_bt<<<512, 256, 0, stream>>>(ao, owbf, b_out, out, nullptr,
                                   8192, 1024, 1024, 0);
}

// Round 21
// 177.233 us; speedup vs baseline: 1.0630x; 1.0630x over previous
//
#include <hip/hip_runtime.h>
#include <hip/hip_bf16.h>
#include <cstdint>

typedef unsigned short u16;
typedef unsigned int   u32;
typedef __bf16  bf16x8 __attribute__((ext_vector_type(8)));
typedef __bf16  bf16x2 __attribute__((ext_vector_type(2)));
typedef float   f32x4  __attribute__((ext_vector_type(4)));
typedef unsigned short u16x4 __attribute__((ext_vector_type(4)));
typedef unsigned short u16x8 __attribute__((ext_vector_type(8)));
typedef unsigned int   u32x2 __attribute__((ext_vector_type(2)));

#define GLB(p) ((__attribute__((address_space(1))) void*)(p))
#define LDSP(p) ((__attribute__((address_space(3))) void*)(p))

__device__ __forceinline__ u16 f2bf(float f) {
  u32 u = __builtin_bit_cast(u32, f);
  u32 r = u + 0x7fffu + ((u >> 16) & 1u);
  return (u16)(r >> 16);
}

// raw 2^x via the COMPILER-VISIBLE builtin (hazard-safe; R13 lesson).
__device__ __forceinline__ float fexp2(float x) {
#if __has_builtin(__builtin_amdgcn_exp2f)
  return __builtin_amdgcn_exp2f(x);
#else
  float r;
  asm volatile("v_exp_f32 %0, %1\n\ts_nop 1" : "=v"(r) : "v"(x));
  return r;
#endif
}

__device__ __forceinline__ void cvt8(const float* __restrict__ in,
                                     u16* __restrict__ out, int i) {
  f32x4 a = *(const f32x4*)(in + i);
  f32x4 b = *(const f32x4*)(in + i + 4);
  u16x8 o;
#pragma unroll
  for (int j = 0; j < 4; ++j) { o[j] = f2bf(a[j]); o[4 + j] = f2bf(b[j]); }
  *(u16x8*)(out + i) = o;
}

// ---- fused prep: x/w_in/w_out f32->bf16 + mask->weights (1 launch) ----
__global__ __launch_bounds__(256) void prep(
    const float* __restrict__ x, u16* __restrict__ xbf,
    const float* __restrict__ wi, u16* __restrict__ wbf,
    const float* __restrict__ wo, u16* __restrict__ owbf,
    const float* __restrict__ mask, float* __restrict__ wf,
    u16* __restrict__ wpb) {
  const int blk = blockIdx.x, tid = threadIdx.x;
  if (blk < 4096) {
    cvt8(x, xbf, (blk * 256 + tid) * 8);
  } else if (blk < 5632) {
    cvt8(wi, wbf, ((blk - 4096) * 256 + tid) * 8);
  } else if (blk < 6144) {
    cvt8(wo, owbf, ((blk - 5632) * 256 + tid) * 8);
  } else {
    int i = (blk - 6144) * 256 + tid;
    float m = mask[i] * 1.4426950408889634f - 8.0f;
    float w = exp2f(m);
    wf[i] = w;
    int lp = (((i >> 2) & 3) << 3) | (((i >> 4) & 1) << 2) | (i & 3);
    wpb[(i & ~31) | lp] = f2bf(w);
  }
}

// ---------------- GEMM C = A * B^T (+bias), bf16 MFMA ----------------
// R18-measured-best: BK=64, two-barrier loop. B rows PERMUTED AT STAGING
// (proven 0-conflict reads + packed coalesced stores). XCD swizzle: each XCD
// owns contiguous m-blocks (A L2-resident), streams B. mode 1: pack qkv
// [sect][b][h][t][d], Q pre-scaled by log2e/8.
__global__ __launch_bounds__(256) void gemm_bt(
    const u16* __restrict__ A, const u16* __restrict__ B,
    const float* __restrict__ bias,
    float* __restrict__ Cf, u16* __restrict__ Cq,
    int M, int N, int K, int mode) {
  __shared__ char lds[32768];
  char* ldsA = lds;
  char* ldsB = lds + 16384;
  const int tid  = threadIdx.x;
  const int lane = tid & 63;
  const int wave = tid >> 6;

  const int lin = blockIdx.x;
  const int cpx = gridDim.x >> 3;
  const int w   = (lin & 7) * cpx + (lin >> 3);
  const int NB  = N >> 7;
  const int m0  = (w / NB) * 128;
  const int n0  = (w % NB) * 128;

  const int wr = (wave >> 1) * 64;
  const int wc = (wave & 1) * 64;

  const u16* gA[4];
  const u16* gB[4];
#pragma unroll
  for (int it = 0; it < 4; ++it) {
    int c  = it * 256 + tid;
    int r  = c >> 3;
    int ch = (c & 7) ^ (r & 7);
    int bsrc = 64 * (r >> 6) + 4 * (r & 15) + ((r >> 4) & 3);  // B col perm
    gA[it] = A + (size_t)(m0 + r) * K + ch * 8;
    gB[it] = B + (size_t)(n0 + bsrc) * K + ch * 8;
  }

  f32x4 acc[4][4] = {};

  const int arow  = wr + (lane & 15);
  const int brow  = wc + (lane & 15);
  const int kswz  = (lane & 7) << 4;
  const int kbyte = (lane >> 4) * 16;

  for (int kk = 0; kk < K; kk += 64) {
    __syncthreads();
#pragma unroll
    for (int it = 0; it < 4; ++it) {
      int c = it * 256 + tid;
      __builtin_amdgcn_global_load_lds(GLB(gA[it] + kk), LDSP(ldsA + c * 16), 16, 0, 0);
      __builtin_amdgcn_global_load_lds(GLB(gB[it] + kk), LDSP(ldsB + c * 16), 16, 0, 0);
    }
    __syncthreads();
#pragma unroll
    for (int s = 0; s < 2; ++s) {
      bf16x8 af[4], bfr[4];
#pragma unroll
      for (int i = 0; i < 4; ++i)
        af[i] = *(const bf16x8*)(ldsA + (arow + i * 16) * 128 + ((kbyte + s * 64) ^ kswz));
#pragma unroll
      for (int j = 0; j < 4; ++j)
        bfr[j] = *(const bf16x8*)(ldsB + (brow + j * 16) * 128 + ((kbyte + s * 64) ^ kswz));
#pragma unroll
      for (int i = 0; i < 4; ++i)
#pragma unroll
        for (int j = 0; j < 4; ++j)
          acc[i][j] = __builtin_amdgcn_mfma_f32_16x16x32_bf16(af[i], bfr[j], acc[i][j], 0, 0, 0);
    }
  }

  const int r0 = m0 + wr + (lane >> 4) * 4;
  const int c0 = n0 + wc + (lane & 15) * 4;   // lane's 4 CONSECUTIVE cols
  f32x4 bv4 = *(const f32x4*)(bias + c0);
  const float qs = (c0 < 1024) ? 0.18033688011112042f : 1.0f;  // Q pre-scale
  const int sect = c0 >> 10, rem = c0 & 1023;
  const int hh = rem >> 6, dd = rem & 63;
#pragma unroll
  for (int i = 0; i < 4; ++i) {
#pragma unroll
    for (int r = 0; r < 4; ++r) {
      int row = r0 + i * 16 + r;
      f32x4 v;
#pragma unroll
      for (int j = 0; j < 4; ++j) v[j] = acc[i][j][r] + bv4[j];
      if (mode == 0) {
        *(f32x4*)(Cf + (size_t)row * N + c0) = v;
      } else {
        u16x4 o;
#pragma unroll
        for (int j = 0; j < 4; ++j) o[j] = f2bf(v[j] * qs);
        int bb = row >> 11, tt = row & 2047;
        *(u16x4*)(Cq + (((((size_t)sect * 4 + bb) * 16 + hh) * 2048 + tt) * 64 + dd)) = o;
      }
    }
  }
}

// ---- V transpose + weight-fold + sigma key-perm: [bh][t][d] -> [bh][d][t'] ----
__global__ __launch_bounds__(256) void transv(const u16* __restrict__ Vp,
                                              u16* __restrict__ Vt,
                                              const float* __restrict__ wf) {
  __shared__ u16 tl[64][68];
  const int tid = threadIdx.x;
  const int bh  = blockIdx.y;
  const int b   = bh >> 4;
  const int t0  = blockIdx.x * 64;
  const u16* src = Vp + ((size_t)bh * 2048 + t0) * 64;
  const float* wrow = wf + (size_t)b * 2048 + t0;
#pragma unroll
  for (int it = 0; it < 2; ++it) {
    int c = it * 256 + tid;
    int r = c >> 3, ch = c & 7;
    u16x8 v = *(const u16x8*)(src + r * 64 + ch * 8);
    float wv = wrow[r];
#pragma unroll
    for (int j = 0; j < 8; ++j) {
      float f = __builtin_bit_cast(float, ((u32)v[j]) << 16) * wv;
      tl[r][ch * 8 + j] = f2bf(f);
    }
  }
  __syncthreads();
  u16* dst = Vt + (size_t)bh * 64 * 2048 + t0;
#pragma unroll
  for (int it = 0; it < 2; ++it) {
    int c = it * 256 + tid;
    int d = c >> 3, ch = c & 7;
    int base = 32 * (ch >> 2) + 4 * (ch & 3);
    u16x8 v;
#pragma unroll
    for (int j = 0; j < 8; ++j) v[j] = tl[base + 16 * (j >> 2) + (j & 3)][d];
    *(u16x8*)(dst + (size_t)d * 2048 + ch * 8) = v;
  }
}

// ---- flash attention fwd (R18 measured-best, unchanged) ----
__global__ __launch_bounds__(512, 8) void attn_fwd(
    const u16* __restrict__ Qp, const u16* __restrict__ Kp,
    const u16* __restrict__ Vt, const u16* __restrict__ wpb,
    u16* __restrict__ AO) {
  __shared__ char lds[36864];
  const int tid  = threadIdx.x;
  const int lane = tid & 63;
  const int wave = tid >> 6;
  const int q15  = lane & 15;
  const int g    = lane >> 4;
  const int sw   = lane & 7;

  const int s  = blockIdx.x;
  const int w  = (s & 7) * 128 + (s >> 3);
  const int qt = w & 15;
  const int bh = w >> 4;
  const int b  = bh >> 4;
  const int h  = bh & 15;
  const int q0 = qt * 128;

  const u16* Qbase = Qp + ((size_t)bh * 2048 + q0) * 64;
  const u16* Kbase = Kp + (size_t)bh * 2048 * 64;
  const u16* Vbase = Vt + (size_t)bh * 64 * 2048;
  const u16* wrow  = wpb + (size_t)b * 2048;

  const u16* gK;
  const u16* gV;
  int ldso;
  {
    int c = tid;
    int r = c >> 3;
    int ch = (c & 7) ^ (r & 7);
    gK = Kbase + (size_t)r * 64 + ch * 8;
    gV = Vbase + (size_t)r * 2048 + ch * 8;
    ldso = c * 16;
  }

#define STAGE(SEL, KVV)                                                        \
  do {                                                                         \
    __builtin_amdgcn_global_load_lds(GLB(gK + (size_t)(KVV) * 64),             \
                                     LDSP(lds + (SEL) * 8192 + ldso), 16, 0, 0); \
    __builtin_amdgcn_global_load_lds(GLB(gV + (KVV)),                          \
                                     LDSP(lds + 16384 + (SEL) * 8192 + ldso), 16, 0, 0); \
  } while (0)

  bf16x8 qa0, qa1;
  {
    int qrow = wave * 16 + q15;
    qa0 = __builtin_bit_cast(bf16x8, *(const u16x8*)(Qbase + qrow * 64 + 8 * g));
    qa1 = __builtin_bit_cast(bf16x8, *(const u16x8*)(Qbase + qrow * 64 + 32 + 8 * g));
  }

  f32x4 oacc0 = {}, oacc1 = {}, oacc2 = {}, oacc3 = {};
  f32x4 lsum = {};
  const f32x4 z4 = {};

  const int koff0 = ((g) ^ sw) << 4;
  const int koff1 = ((4 + g) ^ sw) << 4;
  const char* pk0 = lds + q15 * 128 + koff0;
  const char* pk1 = lds + q15 * 128 + koff1;
  const char* pv0 = lds + 16384 + q15 * 128 + koff0;
  const char* pv1 = lds + 16384 + q15 * 128 + koff1;
  const char* pw  = lds + 32768 + 16 * g;

#define MFMA16(A, B, C) __builtin_amdgcn_mfma_f32_16x16x32_bf16((A), (B), (C), 0, 0, 0)

#define COMPUTE(SEL, KVV)                                                      \
  do {                                                                         \
    f32x4 sv0, sv1, sv2, sv3;                                                  \
    sv0 = MFMA16(*(const bf16x8*)(pk0 + (SEL) * 8192 + 0 * 2048), qa0, z4);    \
    sv0 = MFMA16(*(const bf16x8*)(pk1 + (SEL) * 8192 + 0 * 2048), qa1, sv0);   \
    sv1 = MFMA16(*(const bf16x8*)(pk0 + (SEL) * 8192 + 1 * 2048), qa0, z4);    \
    sv1 = MFMA16(*(const bf16x8*)(pk1 + (SEL) * 8192 + 1 * 2048), qa1, sv1);   \
    sv2 = MFMA16(*(const bf16x8*)(pk0 + (SEL) * 8192 + 2 * 2048), qa0, z4);    \
    sv2 = MFMA16(*(const bf16x8*)(pk1 + (SEL) * 8192 + 2 * 2048), qa1, sv2);   \
    sv3 = MFMA16(*(const bf16x8*)(pk0 + (SEL) * 8192 + 3 * 2048), qa0, z4);    \
    sv3 = MFMA16(*(const bf16x8*)(pk1 + (SEL) * 8192 + 3 * 2048), qa1, sv3);   \
    _Pragma("unroll") for (int i = 0; i < 4; ++i) {                            \
      sv0[i] = fexp2(sv0[i]);                                                  \
      sv1[i] = fexp2(sv1[i]);                                                  \
      sv2[i] = fexp2(sv2[i]);                                                  \
      sv3[i] = fexp2(sv3[i]);                                                  \
    }                                                                          \
    bf16x8 pa0, pa1;                                                           \
    {                                                                          \
      u16x8 t0, t1;                                                            \
      _Pragma("unroll") for (int e = 0; e < 4; ++e) {                          \
        t0[e]     = __builtin_bit_cast(u16, (__bf16)sv0[e]);                   \
        t0[4 + e] = __builtin_bit_cast(u16, (__bf16)sv1[e]);                   \
        t1[e]     = __builtin_bit_cast(u16, (__bf16)sv2[e]);                   \
        t1[4 + e] = __builtin_bit_cast(u16, (__bf16)sv3[e]);                   \
      }                                                                        \
      pa0 = __builtin_bit_cast(bf16x8, t0);                                    \
      pa1 = __builtin_bit_cast(bf16x8, t1);                                    \
    }                                                                          \
    lsum = MFMA16(*(const bf16x8*)(pw + (KVV) * 2), pa0, lsum);                \
    lsum = MFMA16(*(const bf16x8*)(pw + (KVV) * 2 + 64), pa1, lsum);           \
    oacc0 = MFMA16(*(const bf16x8*)(pv0 + (SEL) * 8192 + 0 * 2048), pa0, oacc0); \
    oacc0 = MFMA16(*(const bf16x8*)(pv1 + (SEL) * 8192 + 0 * 2048), pa1, oacc0); \
    oacc1 = MFMA16(*(const bf16x8*)(pv0 + (SEL) * 8192 + 1 * 2048), pa0, oacc1); \
    oacc1 = MFMA16(*(const bf16x8*)(pv1 + (SEL) * 8192 + 1 * 2048), pa1, oacc1); \
    oacc2 = MFMA16(*(const bf16x8*)(pv0 + (SEL) * 8192 + 2 * 2048), pa0, oacc2); \
    oacc2 = MFMA16(*(const bf16x8*)(pv1 + (SEL) * 8192 + 2 * 2048), pa1, oacc2); \
    oacc3 = MFMA16(*(const bf16x8*)(pv0 + (SEL) * 8192 + 3 * 2048), pa0, oacc3); \
    oacc3 = MFMA16(*(const bf16x8*)(pv1 + (SEL) * 8192 + 3 * 2048), pa1, oacc3); \
  } while (0)

  STAGE(0, 0);
  if (tid < 256)
    __builtin_amdgcn_global_load_lds(GLB(wrow + tid * 8), LDSP(lds + 32768 + tid * 16), 16, 0, 0);
  __syncthreads();

  for (int kv = 0; kv < 2048; kv += 128) {
    if (kv + 64 < 2048) STAGE(1, kv + 64);
    COMPUTE(0, kv);
    __syncthreads();
    if (kv + 128 < 2048) STAGE(0, kv + 128);
    COMPUTE(1, kv + 64);
    __syncthreads();
  }

  float linv = 1.0f / lsum[0];
  int t = q0 + wave * 16 + q15;
  u16* aorow = AO + ((size_t)b * 2048 + t) * 1024 + h * 64 + 4 * g;
#pragma unroll
  for (int n = 0; n < 4; ++n) {
    const f32x4& oc = (n == 0) ? oacc0 : (n == 1) ? oacc1 : (n == 2) ? oacc2 : oacc3;
    bf16x2 lo = {(__bf16)(oc[0] * linv), (__bf16)(oc[1] * linv)};
    bf16x2 hi = {(__bf16)(oc[2] * linv), (__bf16)(oc[3] * linv)};
    *(u32*)(aorow + 16 * n)     = __builtin_bit_cast(u32, lo);
    *(u32*)(aorow + 16 * n + 2) = __builtin_bit_cast(u32, hi);
  }
#undef STAGE
#undef COMPUTE
#undef MFMA16
}

// ---------------- launch ----------------
extern "C" void kernel_launch(void* const* d_in, const int* in_sizes, int n_in,
                              void* d_out, int out_size, void* d_ws, size_t ws_size,
                              hipStream_t stream) {
  const float* x     = (const float*)d_in[0];
  const float* mask  = (const float*)d_in[1];
  const float* w_in  = (const float*)d_in[2];
  const float* b_in  = (const float*)d_in[3];
  const float* w_out = (const float*)d_in[4];
  const float* b_out = (const float*)d_in[5];
  float* out = (float*)d_out;

  u16* xbf  = (u16*)d_ws;
  u16* wbf  = xbf  + (size_t)8192 * 1024;
  u16* owbf = wbf  + (size_t)3072 * 1024;
  u16* qkvp = owbf + (size_t)1024 * 1024;
  u16* vt   = qkvp + (size_t)3 * 8192 * 1024;
  u16* ao   = vt   + (size_t)8192 * 1024;
  float* wf = (float*)(ao + (size_t)8192 * 1024);
  u16* wpb  = (u16*)(wf + 8192);

  prep<<<6176, 256, 0, stream>>>(x, xbf, w_in, wbf, w_out, owbf, mask, wf, wpb);

  gemm_bt<<<1536, 256, 0, stream>>>(xbf, wbf, b_in, nullptr, qkvp,
                                    8192, 3072, 1024, 1);
  transv<<<dim3(32, 64), 256, 0, stream>>>(qkvp + (size_t)2 * 8192 * 1024, vt, wf);
  attn_fwd<<<1024, 512, 0, stream>>>(qkvp, qkvp + (size_t)8192 * 1024,
                                     vt, wpb, ao);
  gemm_bt<<<512, 256, 0, stream>>>(ao, owbf, b_out, out, nullptr,
                                   8192, 1024, 1024, 0);
}